// Round 4
// baseline (829.368 us; speedup 1.0000x reference)
//
#include <hip/hip_runtime.h>
#include <stdint.h>

#define NN 4096
#define NITER 10
#define ROWS 16
#define NBLK (NN / ROWS)   // 256 blocks == 256 CUs

static __device__ __forceinline__ unsigned short f2bf(float f) {
  union { float f; unsigned int i; } x; x.f = f;
  unsigned int i = x.i;
  i += 0x7FFFu + ((i >> 16) & 1u);   // round-to-nearest-even
  return (unsigned short)(i >> 16);
}
static __device__ __forceinline__ unsigned int pk2(float a, float b) {
  return (unsigned int)f2bf(a) | ((unsigned int)f2bf(b) << 16);
}
static __device__ __forceinline__ float2 unpk(unsigned int u) {
  union { unsigned int i; float f; } a, b;
  a.i = u << 16; b.i = u & 0xFFFF0000u;
  return make_float2(a.f, b.f);
}
static __device__ __forceinline__ float read_eps(const void* p) {
  float f = *(const float*)p;
  if (f > 1e-4f && f < 1.0f) return f;
  union { unsigned int i; float f; } x;
  x.i = ((unsigned int)*(const unsigned short*)p) << 16;
  return x.f;
}

// flags must be 0 before the persistent kernel; ws is poisoned 0xAA, so zero
// them in a separate stream-ordered launch (no race with the spin barrier).
__global__ __launch_bounds__(256) void zero_flags(int* __restrict__ flags) {
  flags[threadIdx.x] = 0;
}

// all-see-all device barrier: block b publishes token in flags[b]; thread t
// polls flags[t] (blockDim == NBLK == 256). Tokens strictly increase -> no
// reset needed, late blocks see ">= token" from racing-ahead blocks safely.
static __device__ __forceinline__ void dev_barrier(int* flags, int token) {
  __syncthreads();
  if (threadIdx.x == 0) {
    __threadfence();   // release all prior global writes (device scope)
    __hip_atomic_store(flags + blockIdx.x, token, __ATOMIC_RELAXED,
                       __HIP_MEMORY_SCOPE_AGENT);
  }
  while (__hip_atomic_load(flags + threadIdx.x, __ATOMIC_RELAXED,
                           __HIP_MEMORY_SCOPE_AGENT) < token)
    __builtin_amdgcn_s_sleep(1);
  __threadfence();     // acquire
  __syncthreads();
}

// ---------------------------------------------------------------------------
// One persistent block per 16 rows. LDS map (floats):
//   [0..16383]    staged v (swizzled float4 slots), restaged every iteration
//   [0..1023]     phase-C reduction buffer (v no longer needed then)
//   [1024..1087]  u for this block's 16 rows  [row-local n][s]
//   [1088..1151]  v for this block's 16 cols  [mloc][s] (for finalize)
__global__ __launch_bounds__(256, 1) void sinkhorn_all(
    const float* __restrict__ alpha, const float* __restrict__ beta,
    const float* __restrict__ C, const void* __restrict__ epsp,
    unsigned short* __restrict__ K, float* __restrict__ partial,
    float* __restrict__ v_t, int* __restrict__ flags,
    float* __restrict__ out) {
  __shared__ float v_lds[NN * 4];   // 64 KiB
  const int t = threadIdx.x, b = blockIdx.x;
  const int wave = t >> 6, lane = t & 63, sw = lane & 7;
  const int row0 = b * ROWS;
  const float eps = read_eps(epsp);
  const float nie = -1.0f / eps;

  // ---- phase 0: build this block's 16 K rows (bf16), init v slice = 1 ----
#pragma unroll 2
  for (int r = 0; r < ROWS; ++r) {
    const float4* Crow = (const float4*)(C + (size_t)(row0 + r) * NN) + t * 4;
    float4 c0 = Crow[0], c1 = Crow[1], c2 = Crow[2], c3 = Crow[3];
    uint4 k0, k1;
    k0.x = pk2(__expf(c0.x * nie), __expf(c0.y * nie));
    k0.y = pk2(__expf(c0.z * nie), __expf(c0.w * nie));
    k0.z = pk2(__expf(c1.x * nie), __expf(c1.y * nie));
    k0.w = pk2(__expf(c1.z * nie), __expf(c1.w * nie));
    k1.x = pk2(__expf(c2.x * nie), __expf(c2.y * nie));
    k1.y = pk2(__expf(c2.z * nie), __expf(c2.w * nie));
    k1.z = pk2(__expf(c3.x * nie), __expf(c3.y * nie));
    k1.w = pk2(__expf(c3.z * nie), __expf(c3.w * nie));
    uint4* Krow = (uint4*)(K + (size_t)(row0 + r) * NN);
    Krow[t * 2] = k0;
    Krow[t * 2 + 1] = k1;
  }
  if (t < 16) ((float4*)v_t)[b * 16 + t] = make_float4(1.f, 1.f, 1.f, 1.f);
  dev_barrier(flags, 1);

  for (int it = 0; it < NITER; ++it) {
    // ---- stage v into LDS (xor-swizzled float4 slots) ----
    {
      const float4* V = (const float4*)v_t;
      float4* L = (float4*)v_lds;
#pragma unroll
      for (int k = 0; k < 16; ++k) {
        int idx = t + k * 256;
        L[idx ^ ((idx >> 3) & 7)] = V[idx];
      }
    }
    __syncthreads();

    // ---- phase A: row dots over own 16 rows; u = alpha / rowsum ----
    float acc[4][4] = {};
    const int r0 = row0 + wave * 4;
    const uint4* Kr0 = (const uint4*)(K + (size_t)r0 * NN);
    const float4* VL = (const float4*)v_lds;
#pragma unroll 2
    for (int mb = 0; mb < 8; ++mb) {
      int m0 = mb * 512 + lane * 8;
      uint4 karr[4];
      karr[0] = Kr0[(m0 >> 3)];
      karr[1] = Kr0[(m0 >> 3) + 512];
      karr[2] = Kr0[(m0 >> 3) + 1024];
      karr[3] = Kr0[(m0 >> 3) + 1536];
      float4 vv[8];
#pragma unroll
      for (int j = 0; j < 8; ++j) vv[j] = VL[m0 + (j ^ sw)];  // vv[j] = col m0+j
#pragma unroll
      for (int r = 0; r < 4; ++r) {
        unsigned int cw[4] = {karr[r].x, karr[r].y, karr[r].z, karr[r].w};
#pragma unroll
        for (int w = 0; w < 4; ++w) {
          float2 f = unpk(cw[w]);
          float4 va = vv[2 * w], vb = vv[2 * w + 1];
          acc[r][0] += f.x * va.x; acc[r][1] += f.x * va.y;
          acc[r][2] += f.x * va.z; acc[r][3] += f.x * va.w;
          acc[r][0] += f.y * vb.x; acc[r][1] += f.y * vb.y;
          acc[r][2] += f.y * vb.z; acc[r][3] += f.y * vb.w;
        }
      }
    }
#pragma unroll
    for (int off = 32; off > 0; off >>= 1)
#pragma unroll
      for (int r = 0; r < 4; ++r)
#pragma unroll
        for (int s = 0; s < 4; ++s)
          acc[r][s] += __shfl_xor(acc[r][s], off);
    __syncthreads();   // v reads complete before u overlays LDS
    if (lane < 16) {
      int rl = lane >> 2, s = lane & 3;
      float uval = alpha[s * NN + r0 + rl] / acc[rl][s];
      v_lds[1024 + wave * 16 + lane] = uval;   // [local row][s]
    }
    __syncthreads();

    // ---- phase B: column partials from own 16 rows (L2-hot re-read) ----
    float a2[16][4] = {};
    const unsigned short* Kc = K + (size_t)row0 * NN + t * 16;
#pragma unroll 4
    for (int n = 0; n < ROWS; ++n) {
      float4 u4 = ((const float4*)v_lds)[256 + n];   // broadcast
      const uint4* kp = (const uint4*)(Kc + (size_t)n * NN);
      uint4 ka = kp[0], kb = kp[1];
      unsigned int aw[4] = {ka.x, ka.y, ka.z, ka.w};
      unsigned int bw[4] = {kb.x, kb.y, kb.z, kb.w};
#pragma unroll
      for (int w = 0; w < 4; ++w) {
        float2 fa = unpk(aw[w]);
        a2[2*w][0]   += fa.x * u4.x; a2[2*w][1]   += fa.x * u4.y;
        a2[2*w][2]   += fa.x * u4.z; a2[2*w][3]   += fa.x * u4.w;
        a2[2*w+1][0] += fa.y * u4.x; a2[2*w+1][1] += fa.y * u4.y;
        a2[2*w+1][2] += fa.y * u4.z; a2[2*w+1][3] += fa.y * u4.w;
        float2 fb = unpk(bw[w]);
        a2[8+2*w][0] += fb.x * u4.x; a2[8+2*w][1] += fb.x * u4.y;
        a2[8+2*w][2] += fb.x * u4.z; a2[8+2*w][3] += fb.x * u4.w;
        a2[9+2*w][0] += fb.y * u4.x; a2[9+2*w][1] += fb.y * u4.y;
        a2[9+2*w][2] += fb.y * u4.z; a2[9+2*w][3] += fb.y * u4.w;
      }
    }
    {
      float4* P = (float4*)partial + (size_t)b * NN + t * 16;
#pragma unroll
      for (int j = 0; j < 16; ++j)
        P[j] = make_float4(a2[j][0], a2[j][1], a2[j][2], a2[j][3]);
    }
    dev_barrier(flags, 2 + it * 2);

    // ---- phase C: reduce partials for own 16 cols; v = beta / colsum ----
    {
      const int bgrp = t >> 4, mloc = t & 15;
      const int m = b * 16 + mloc;
      const float4* P4 = (const float4*)partial;
      float4 s4 = make_float4(0.f, 0.f, 0.f, 0.f);
#pragma unroll 4
      for (int i = 0; i < 16; ++i) {
        int bsrc = i * 16 + bgrp;
        float4 p = P4[(size_t)bsrc * NN + m];
        s4.x += p.x; s4.y += p.y; s4.z += p.z; s4.w += p.w;
      }
      float4* red = (float4*)v_lds;   // floats 0..1023, v no longer needed
      red[t] = s4;
      __syncthreads();
      if (t < 16) {
        float4 a = red[t];
#pragma unroll
        for (int g = 1; g < 16; ++g) {
          float4 r = red[g * 16 + t];
          a.x += r.x; a.y += r.y; a.z += r.z; a.w += r.w;
        }
        int mm = b * 16 + t;
        float4 res;
        res.x = beta[0 * NN + mm] / a.x;
        res.y = beta[1 * NN + mm] / a.y;
        res.z = beta[2 * NN + mm] / a.z;
        res.w = beta[3 * NN + mm] / a.w;
        ((float4*)v_t)[mm] = res;
        ((float4*)v_lds)[272 + t] = res;   // stash for finalize
      }
    }
    if (it < NITER - 1) dev_barrier(flags, 3 + it * 2);
  }
  __syncthreads();

  // ---- finalize (all block-local): f from u-stash, g from v-stash ----
  if (t < 64) {
    int s = t >> 4, nloc = t & 15;
    float u = v_lds[1024 + nloc * 4 + s];
    out[s * NN + row0 + nloc] = eps * __logf(u);
  } else if (t < 128) {
    int tt = t - 64, s = tt >> 4, mloc = tt & 15;
    float v = v_lds[1088 + mloc * 4 + s];
    out[4 * NN + s * NN + b * 16 + mloc] = eps * __logf(v);
  }
}

// ---------------------------------------------------------------------------
extern "C" void kernel_launch(void* const* d_in, const int* in_sizes, int n_in,
                              void* d_out, int out_size, void* d_ws, size_t ws_size,
                              hipStream_t stream) {
  (void)in_sizes; (void)n_in; (void)out_size; (void)ws_size;
  const float* alpha = (const float*)d_in[0];   // f32 (4,4096)
  const float* beta  = (const float*)d_in[1];   // f32 (4,4096)
  const float* C     = (const float*)d_in[2];   // f32 (4096,4096)
  const void*  epsp  = d_in[3];                 // f32 scalar

  char* ws = (char*)d_ws;
  unsigned short* K = (unsigned short*)ws;                       // 32 MiB
  float* partial    = (float*)(ws + 33554432);                   // 16 MiB
  float* v_t        = (float*)(ws + 33554432 + 16777216);        // 64 KiB
  int* flags        = (int*)(ws + 33554432 + 16777216 + 65536);  // 1 KiB
  float* out = (float*)d_out;

  zero_flags<<<1, 256, 0, stream>>>(flags);
  sinkhorn_all<<<NBLK, 256, 0, stream>>>(alpha, beta, C, epsp, K, partial,
                                         v_t, flags, out);
}

// Round 5
// 758.566 us; speedup vs baseline: 1.0933x; 1.0933x over previous
//
#include <hip/hip_runtime.h>
#include <stdint.h>

#define NN 4096
#define NITER 10
#define ROWS 16
#define NBLK (NN / ROWS)   // 256 blocks (== CU count, all co-resident)
#define NTOK 24

static __device__ __forceinline__ unsigned short f2bf(float f) {
  union { float f; unsigned int i; } x; x.f = f;
  unsigned int i = x.i;
  i += 0x7FFFu + ((i >> 16) & 1u);   // round-to-nearest-even
  return (unsigned short)(i >> 16);
}
static __device__ __forceinline__ unsigned int pk2(float a, float b) {
  return (unsigned int)f2bf(a) | ((unsigned int)f2bf(b) << 16);
}
static __device__ __forceinline__ float2 unpk(unsigned int u) {
  union { unsigned int i; float f; } a, b;
  a.i = u << 16; b.i = u & 0xFFFF0000u;
  return make_float2(a.f, b.f);
}
static __device__ __forceinline__ float read_eps(const void* p) {
  float f = *(const float*)p;
  if (f > 1e-4f && f < 1.0f) return f;
  union { unsigned int i; float f; } x;
  x.i = ((unsigned int)*(const unsigned short*)p) << 16;
  return x.f;
}

// ws is poisoned 0xAA before every timed launch -> zero the barrier counters
// in a stream-ordered pre-launch (no race with the persistent kernel).
__global__ __launch_bounds__(64) void zero_ctrs(unsigned int* __restrict__ c) {
  if (threadIdx.x < NTOK) c[threadIdx.x] = 0;
}

// Lightweight grid barrier: per-token counter, one RMW + one poller per block.
// Release-RMW flushes only this XCD's dirty L2 (tiny: 256 B of u/v per block).
static __device__ __forceinline__ void grid_barrier(unsigned int* ctrs, int token) {
  __syncthreads();
  if (threadIdx.x == 0) {
    __hip_atomic_fetch_add(&ctrs[token], 1u, __ATOMIC_RELEASE,
                           __HIP_MEMORY_SCOPE_AGENT);
    while (__hip_atomic_load(&ctrs[token], __ATOMIC_RELAXED,
                             __HIP_MEMORY_SCOPE_AGENT) < (unsigned)NBLK)
      __builtin_amdgcn_s_sleep(8);
    __builtin_amdgcn_fence(__ATOMIC_ACQUIRE, "agent");  // inv L1+L2 (CU/XCD-wide)
  }
  __syncthreads();
}

// ---------------------------------------------------------------------------
// Persistent kernel. Block b owns rows [16b,16b+16) (u-update) and
// columns [16b,16b+16) (v-update). K is read-only after build -> the only
// cross-block traffic per half-step is the 64 KB u or v vector.
__global__ __launch_bounds__(256, 1) void sinkhorn_all(
    const float* __restrict__ alpha, const float* __restrict__ beta,
    const float* __restrict__ C, const void* __restrict__ epsp,
    unsigned short* __restrict__ K, float* __restrict__ u_t,
    float* __restrict__ v_t, unsigned int* __restrict__ ctrs,
    float* __restrict__ out) {
  __shared__ float v_lds[4112 * 4];   // 64.25 KB: v/u staging + acc dump (stride 257)
  __shared__ float4 red2[256];        // 4 KB second-stage reduction
  const int t = threadIdx.x, b = blockIdx.x;
  const int wave = t >> 6, lane = t & 63, sw = lane & 7;
  const int row0 = b * ROWS;
  const float eps = read_eps(epsp);
  const float nie = -1.0f / eps;

  // ---- build own 16 K rows (coalesced from C rows); init own v cols = 1 ----
#pragma unroll 2
  for (int r = 0; r < ROWS; ++r) {
    const float4* Crow = (const float4*)(C + (size_t)(row0 + r) * NN) + t * 4;
    float4 c0 = Crow[0], c1 = Crow[1], c2 = Crow[2], c3 = Crow[3];
    uint4 k0, k1;
    k0.x = pk2(__expf(c0.x * nie), __expf(c0.y * nie));
    k0.y = pk2(__expf(c0.z * nie), __expf(c0.w * nie));
    k0.z = pk2(__expf(c1.x * nie), __expf(c1.y * nie));
    k0.w = pk2(__expf(c1.z * nie), __expf(c1.w * nie));
    k1.x = pk2(__expf(c2.x * nie), __expf(c2.y * nie));
    k1.y = pk2(__expf(c2.z * nie), __expf(c2.w * nie));
    k1.z = pk2(__expf(c3.x * nie), __expf(c3.y * nie));
    k1.w = pk2(__expf(c3.z * nie), __expf(c3.w * nie));
    uint4* Krow = (uint4*)(K + (size_t)(row0 + r) * NN);
    Krow[t * 2] = k0;
    Krow[t * 2 + 1] = k1;
  }
  if (t < 16) ((float4*)v_t)[row0 + t] = make_float4(1.f, 1.f, 1.f, 1.f);
  grid_barrier(ctrs, 1);   // K fully built + v initialized, everywhere

  for (int it = 0; it < NITER; ++it) {
    // ================= phase A: u[n] = alpha[n] / (K v)[n], own 16 rows ====
    {
      const float4* V = (const float4*)v_t;
      float4* L = (float4*)v_lds;
#pragma unroll
      for (int k = 0; k < 16; ++k) {
        int idx = t + k * 256;
        L[idx ^ ((idx >> 3) & 7)] = V[idx];   // xor-swizzled slots
      }
    }
    __syncthreads();
    float acc[4][4] = {};
    const int r0 = row0 + wave * 4;
    const uint4* Kr0 = (const uint4*)(K + (size_t)r0 * NN);
    const float4* VL = (const float4*)v_lds;
#pragma unroll 2
    for (int mb = 0; mb < 8; ++mb) {
      int m0 = mb * 512 + lane * 8;
      uint4 karr[4];
      karr[0] = Kr0[(m0 >> 3)];
      karr[1] = Kr0[(m0 >> 3) + 512];
      karr[2] = Kr0[(m0 >> 3) + 1024];
      karr[3] = Kr0[(m0 >> 3) + 1536];
      float4 vv[8];
#pragma unroll
      for (int j = 0; j < 8; ++j) vv[j] = VL[m0 + (j ^ sw)];  // vv[j] = col m0+j
#pragma unroll
      for (int r = 0; r < 4; ++r) {
        unsigned int cw[4] = {karr[r].x, karr[r].y, karr[r].z, karr[r].w};
#pragma unroll
        for (int w = 0; w < 4; ++w) {
          float2 f = unpk(cw[w]);
          float4 va = vv[2 * w], vb = vv[2 * w + 1];
          acc[r][0] += f.x * va.x; acc[r][1] += f.x * va.y;
          acc[r][2] += f.x * va.z; acc[r][3] += f.x * va.w;
          acc[r][0] += f.y * vb.x; acc[r][1] += f.y * vb.y;
          acc[r][2] += f.y * vb.z; acc[r][3] += f.y * vb.w;
        }
      }
    }
#pragma unroll
    for (int off = 32; off > 0; off >>= 1)
#pragma unroll
      for (int r = 0; r < 4; ++r)
#pragma unroll
        for (int s = 0; s < 4; ++s)
          acc[r][s] += __shfl_xor(acc[r][s], off);
    if (lane < 16) {
      int rl = lane >> 2, s = lane & 3;
      int row = r0 + rl;
      float uval = alpha[s * NN + row] / acc[rl][s];
      u_t[row * 4 + s] = uval;
      if (it == NITER - 1) out[s * NN + row] = eps * __logf(uval);
    }
    grid_barrier(ctrs, 2 + 2 * it);   // u published everywhere

    // ================= phase B: v[m] = beta[m] / (K^T u)[m], own 16 cols ===
    {
      const float4* U = (const float4*)u_t;
      float4* L = (float4*)v_lds;
#pragma unroll
      for (int k = 0; k < 16; ++k) {
        int idx = t + k * 256;
        L[idx] = U[idx];                      // linear slots
      }
    }
    __syncthreads();
    float a2[16][4] = {};
#pragma unroll 4
    for (int i = 0; i < 16; ++i) {
      int n = i * 256 + t;
      float4 u4 = ((const float4*)v_lds)[n];
      const uint4* kp = (const uint4*)(K + (size_t)n * NN + row0);  // 32B, aligned
      uint4 ka = kp[0], kb = kp[1];
      unsigned int aw[4] = {ka.x, ka.y, ka.z, ka.w};
      unsigned int bw[4] = {kb.x, kb.y, kb.z, kb.w};
#pragma unroll
      for (int w = 0; w < 4; ++w) {
        float2 fa = unpk(aw[w]);
        a2[2*w][0]   += fa.x * u4.x; a2[2*w][1]   += fa.x * u4.y;
        a2[2*w][2]   += fa.x * u4.z; a2[2*w][3]   += fa.x * u4.w;
        a2[2*w+1][0] += fa.y * u4.x; a2[2*w+1][1] += fa.y * u4.y;
        a2[2*w+1][2] += fa.y * u4.z; a2[2*w+1][3] += fa.y * u4.w;
        float2 fb = unpk(bw[w]);
        a2[8+2*w][0] += fb.x * u4.x; a2[8+2*w][1] += fb.x * u4.y;
        a2[8+2*w][2] += fb.x * u4.z; a2[8+2*w][3] += fb.x * u4.w;
        a2[9+2*w][0] += fb.y * u4.x; a2[9+2*w][1] += fb.y * u4.y;
        a2[9+2*w][2] += fb.y * u4.z; a2[9+2*w][3] += fb.y * u4.w;
      }
    }
    __syncthreads();   // all u reads done; reuse v_lds for the acc dump
    {
      float4* D = (float4*)v_lds;
#pragma unroll
      for (int j = 0; j < 16; ++j)   // stride 257: conflict-free writes
        D[j * 257 + t] = make_float4(a2[j][0], a2[j][1], a2[j][2], a2[j][3]);
    }
    __syncthreads();
    {
      int jj = t & 15, pp = t >> 4;
      const float4* D = (const float4*)v_lds;
      float4 ps = make_float4(0.f, 0.f, 0.f, 0.f);
#pragma unroll
      for (int c = 0; c < 16; ++c) {
        float4 q = D[jj * 257 + pp * 16 + c];
        ps.x += q.x; ps.y += q.y; ps.z += q.z; ps.w += q.w;
      }
      red2[jj * 16 + pp] = ps;
    }
    __syncthreads();
    if (t < 16) {
      float4 a = make_float4(0.f, 0.f, 0.f, 0.f);
#pragma unroll
      for (int p = 0; p < 16; ++p) {
        float4 r = red2[t * 16 + p];
        a.x += r.x; a.y += r.y; a.z += r.z; a.w += r.w;
      }
      int m = row0 + t;
      float4 res;
      res.x = beta[0 * NN + m] / a.x;
      res.y = beta[1 * NN + m] / a.y;
      res.z = beta[2 * NN + m] / a.z;
      res.w = beta[3 * NN + m] / a.w;
      ((float4*)v_t)[m] = res;
      if (it == NITER - 1) {
        out[4 * NN + 0 * NN + m] = eps * __logf(res.x);
        out[4 * NN + 1 * NN + m] = eps * __logf(res.y);
        out[4 * NN + 2 * NN + m] = eps * __logf(res.z);
        out[4 * NN + 3 * NN + m] = eps * __logf(res.w);
      }
    }
    if (it < NITER - 1) grid_barrier(ctrs, 3 + 2 * it);   // v published
  }
}

// ---------------------------------------------------------------------------
extern "C" void kernel_launch(void* const* d_in, const int* in_sizes, int n_in,
                              void* d_out, int out_size, void* d_ws, size_t ws_size,
                              hipStream_t stream) {
  (void)in_sizes; (void)n_in; (void)out_size; (void)ws_size;
  const float* alpha = (const float*)d_in[0];   // f32 (4,4096)
  const float* beta  = (const float*)d_in[1];   // f32 (4,4096)
  const float* C     = (const float*)d_in[2];   // f32 (4096,4096)
  const void*  epsp  = d_in[3];                 // f32 scalar

  char* ws = (char*)d_ws;
  unsigned short* K  = (unsigned short*)ws;                  // 32 MiB
  float* u_t         = (float*)(ws + 33554432);              // 64 KiB
  float* v_t         = (float*)(ws + 33554432 + 65536);      // 64 KiB
  unsigned int* ctrs = (unsigned int*)(ws + 33554432 + 131072);  // 96 B
  float* out = (float*)d_out;

  zero_ctrs<<<1, 64, 0, stream>>>(ctrs);
  sinkhorn_all<<<NBLK, 256, 0, stream>>>(alpha, beta, C, epsp, K, u_t, v_t,
                                         ctrs, out);
}

// Round 6
// 551.960 us; speedup vs baseline: 1.5026x; 1.3743x over previous
//
#include <hip/hip_runtime.h>
#include <stdint.h>

#define NN 4096
#define NITER 10
#define ROWS 16
#define NBLK 256
#define NTOK 24

static __device__ __forceinline__ unsigned short f2bf(float f) {
  union { float f; unsigned int i; } x; x.f = f;
  unsigned int i = x.i;
  i += 0x7FFFu + ((i >> 16) & 1u);   // round-to-nearest-even
  return (unsigned short)(i >> 16);
}
static __device__ __forceinline__ unsigned int pk2(float a, float b) {
  return (unsigned int)f2bf(a) | ((unsigned int)f2bf(b) << 16);
}
static __device__ __forceinline__ float2 unpk(unsigned int u) {
  union { unsigned int i; float f; } a, b;
  a.i = u << 16; b.i = u & 0xFFFF0000u;
  return make_float2(a.f, b.f);
}
static __device__ __forceinline__ float read_eps(const void* p) {
  float f = *(const float*)p;
  if (f > 1e-4f && f < 1.0f) return f;
  union { unsigned int i; float f; } x;
  x.i = ((unsigned int)*(const unsigned short*)p) << 16;
  return x.f;
}

// --- IC-coherent (agent-scope, L2-bypassing) scalar exchange helpers ------
static __device__ __forceinline__ float2 aload2(const float* p) {
  unsigned long long q = __hip_atomic_load((const unsigned long long*)p,
      __ATOMIC_RELAXED, __HIP_MEMORY_SCOPE_AGENT);
  union { unsigned long long q; float2 f; } u; u.q = q; return u.f;
}
static __device__ __forceinline__ void astore2(float* p, float a, float b) {
  union { unsigned long long q; float2 f; } u; u.f = make_float2(a, b);
  __hip_atomic_store((unsigned long long*)p, u.q, __ATOMIC_RELAXED,
                     __HIP_MEMORY_SCOPE_AGENT);
}
static __device__ __forceinline__ void astore1(float* p, float v) {
  __hip_atomic_store(p, v, __ATOMIC_RELAXED, __HIP_MEMORY_SCOPE_AGENT);
}

// ws is poisoned 0xAA before every timed launch -> zero counters stream-ordered.
__global__ __launch_bounds__(64) void zero_ctrs(unsigned int* __restrict__ c) {
  if (threadIdx.x < NTOK) c[threadIdx.x] = 0;
}

// Light barrier: NO cache-maintenance fences. __syncthreads drains vmcnt
// (all sc1 stores visible at IC); arrive+poll via relaxed agent atomics.
static __device__ __forceinline__ void light_barrier(unsigned int* ctrs, int token) {
  __syncthreads();
  if (threadIdx.x == 0) {
    __hip_atomic_fetch_add(&ctrs[token], 1u, __ATOMIC_RELAXED,
                           __HIP_MEMORY_SCOPE_AGENT);
    while (__hip_atomic_load(&ctrs[token], __ATOMIC_RELAXED,
                             __HIP_MEMORY_SCOPE_AGENT) < (unsigned)NBLK)
      __builtin_amdgcn_s_sleep(2);
  }
  __syncthreads();
}
// Heavy barrier (once, after K build): flush dirty K to IC + invalidate L2s.
static __device__ __forceinline__ void heavy_barrier(unsigned int* ctrs, int token) {
  __syncthreads();
  if (threadIdx.x == 0) {
    __builtin_amdgcn_fence(__ATOMIC_RELEASE, "agent");
    __hip_atomic_fetch_add(&ctrs[token], 1u, __ATOMIC_RELAXED,
                           __HIP_MEMORY_SCOPE_AGENT);
    while (__hip_atomic_load(&ctrs[token], __ATOMIC_RELAXED,
                             __HIP_MEMORY_SCOPE_AGENT) < (unsigned)NBLK)
      __builtin_amdgcn_s_sleep(2);
    __builtin_amdgcn_fence(__ATOMIC_ACQUIRE, "agent");
  }
  __syncthreads();
}

// ---------------------------------------------------------------------------
// Persistent kernel, XCD-banded ownership: own = ((b&7)<<5)|(b>>3) so each
// XCD's 32 blocks own contiguous 512-row and 512-col bands (L2 locality).
// K is built once, fenced once, then stays L2-resident (no more inv).
// u/v cross through the Infinity Cache via relaxed agent atomics.
__global__ __launch_bounds__(256, 1) void sinkhorn_all(
    const float* __restrict__ alpha, const float* __restrict__ beta,
    const float* __restrict__ C, const void* __restrict__ epsp,
    unsigned short* __restrict__ K, float* __restrict__ u_t,
    float* __restrict__ v_t, unsigned int* __restrict__ ctrs,
    float* __restrict__ out) {
  __shared__ float v_lds[4112 * 4];   // 64.25 KB staging / dump (stride 257)
  __shared__ float4 red2[256];
  const int t = threadIdx.x, b = blockIdx.x;
  const int wave = t >> 6, lane = t & 63, sw = lane & 7;
  const int own = ((b & 7) << 5) | (b >> 3);   // banded owner index
  const int base0 = own * ROWS;                // first owned row AND col
  const float eps = read_eps(epsp);
  const float nie = -1.0f / eps;

  // ---- build own 16 K rows; init own v cols = 1 (via IC atomics) ----
#pragma unroll 2
  for (int r = 0; r < ROWS; ++r) {
    const float4* Crow = (const float4*)(C + (size_t)(base0 + r) * NN) + t * 4;
    float4 c0 = Crow[0], c1 = Crow[1], c2 = Crow[2], c3 = Crow[3];
    uint4 k0, k1;
    k0.x = pk2(__expf(c0.x * nie), __expf(c0.y * nie));
    k0.y = pk2(__expf(c0.z * nie), __expf(c0.w * nie));
    k0.z = pk2(__expf(c1.x * nie), __expf(c1.y * nie));
    k0.w = pk2(__expf(c1.z * nie), __expf(c1.w * nie));
    k1.x = pk2(__expf(c2.x * nie), __expf(c2.y * nie));
    k1.y = pk2(__expf(c2.z * nie), __expf(c2.w * nie));
    k1.z = pk2(__expf(c3.x * nie), __expf(c3.y * nie));
    k1.w = pk2(__expf(c3.z * nie), __expf(c3.w * nie));
    uint4* Krow = (uint4*)(K + (size_t)(base0 + r) * NN);
    Krow[t * 2] = k0;
    Krow[t * 2 + 1] = k1;
  }
  if (t < 16) {
    astore2(v_t + (base0 + t) * 4, 1.f, 1.f);
    astore2(v_t + (base0 + t) * 4 + 2, 1.f, 1.f);
  }
  heavy_barrier(ctrs, 1);   // only fenced barrier in the kernel

  for (int it = 0; it < NITER; ++it) {
    // ========== phase A: u[n] = alpha[n]/(K v)[n], own 16 rows ==========
    {
      float4* L = (float4*)v_lds;
#pragma unroll 4
      for (int k = 0; k < 16; ++k) {
        int slot = t + k * 256;
        float2 q0 = aload2(v_t + slot * 4);
        float2 q1 = aload2(v_t + slot * 4 + 2);
        L[slot ^ ((slot >> 3) & 7)] = make_float4(q0.x, q0.y, q1.x, q1.y);
      }
    }
    __syncthreads();
    const int r0 = base0 + wave * 4;
    const uint4* Kr0 = (const uint4*)(K + (size_t)r0 * NN);
    uint4 karr[32];    // full prefetch: 32 outstanding 16-B loads per lane
#pragma unroll
    for (int mb = 0; mb < 8; ++mb) {
      int base = mb * 64 + lane;
      karr[mb * 4 + 0] = Kr0[base];
      karr[mb * 4 + 1] = Kr0[base + 512];
      karr[mb * 4 + 2] = Kr0[base + 1024];
      karr[mb * 4 + 3] = Kr0[base + 1536];
    }
    float acc[4][4] = {};
    const float4* VL = (const float4*)v_lds;
#pragma unroll
    for (int mb = 0; mb < 8; ++mb) {
      int m0 = mb * 512 + lane * 8;
      float4 vv[8];
#pragma unroll
      for (int j = 0; j < 8; ++j) vv[j] = VL[m0 + (j ^ sw)];  // vv[j]=col m0+j
#pragma unroll
      for (int r = 0; r < 4; ++r) {
        unsigned int cw[4] = {karr[mb*4+r].x, karr[mb*4+r].y,
                              karr[mb*4+r].z, karr[mb*4+r].w};
#pragma unroll
        for (int w = 0; w < 4; ++w) {
          float2 f = unpk(cw[w]);
          float4 va = vv[2 * w], vb = vv[2 * w + 1];
          acc[r][0] += f.x * va.x; acc[r][1] += f.x * va.y;
          acc[r][2] += f.x * va.z; acc[r][3] += f.x * va.w;
          acc[r][0] += f.y * vb.x; acc[r][1] += f.y * vb.y;
          acc[r][2] += f.y * vb.z; acc[r][3] += f.y * vb.w;
        }
      }
    }
#pragma unroll
    for (int off = 32; off > 0; off >>= 1)
#pragma unroll
      for (int r = 0; r < 4; ++r)
#pragma unroll
        for (int s = 0; s < 4; ++s)
          acc[r][s] += __shfl_xor(acc[r][s], off);
    if (lane < 16) {
      int rl = lane >> 2, s = lane & 3;
      int row = r0 + rl;
      float uval = alpha[s * NN + row] / acc[rl][s];
      astore1(u_t + row * 4 + s, uval);
      if (it == NITER - 1) out[s * NN + row] = eps * __logf(uval);
    }
    light_barrier(ctrs, 2 + 2 * it);   // u at IC everywhere

    // ========== phase B: v[m] = beta[m]/(K^T u)[m], own 16 cols ==========
    {
      float4* L = (float4*)v_lds;
#pragma unroll 4
      for (int k = 0; k < 16; ++k) {
        int slot = t + k * 256;
        float2 q0 = aload2(u_t + slot * 4);
        float2 q1 = aload2(u_t + slot * 4 + 2);
        L[slot] = make_float4(q0.x, q0.y, q1.x, q1.y);   // linear slots
      }
    }
    __syncthreads();
    uint4 ka[16], kb[16];   // full prefetch of the 16-col strips
#pragma unroll
    for (int i = 0; i < 16; ++i) {
      int n = i * 256 + t;
      const uint4* kp = (const uint4*)(K + (size_t)n * NN + base0);
      ka[i] = kp[0]; kb[i] = kp[1];
    }
    float a2[16][4] = {};
#pragma unroll
    for (int i = 0; i < 16; ++i) {
      float4 u4 = ((const float4*)v_lds)[i * 256 + t];
      unsigned int aw[4] = {ka[i].x, ka[i].y, ka[i].z, ka[i].w};
      unsigned int bw[4] = {kb[i].x, kb[i].y, kb[i].z, kb[i].w};
#pragma unroll
      for (int w = 0; w < 4; ++w) {
        float2 fa = unpk(aw[w]);
        a2[2*w][0]   += fa.x * u4.x; a2[2*w][1]   += fa.x * u4.y;
        a2[2*w][2]   += fa.x * u4.z; a2[2*w][3]   += fa.x * u4.w;
        a2[2*w+1][0] += fa.y * u4.x; a2[2*w+1][1] += fa.y * u4.y;
        a2[2*w+1][2] += fa.y * u4.z; a2[2*w+1][3] += fa.y * u4.w;
        float2 fb = unpk(bw[w]);
        a2[8+2*w][0] += fb.x * u4.x; a2[8+2*w][1] += fb.x * u4.y;
        a2[8+2*w][2] += fb.x * u4.z; a2[8+2*w][3] += fb.x * u4.w;
        a2[9+2*w][0] += fb.y * u4.x; a2[9+2*w][1] += fb.y * u4.y;
        a2[9+2*w][2] += fb.y * u4.z; a2[9+2*w][3] += fb.y * u4.w;
      }
    }
    __syncthreads();   // u reads done; reuse v_lds for the dump
    {
      float4* D = (float4*)v_lds;
#pragma unroll
      for (int j = 0; j < 16; ++j)   // stride 257: conflict-free
        D[j * 257 + t] = make_float4(a2[j][0], a2[j][1], a2[j][2], a2[j][3]);
    }
    __syncthreads();
    {
      int jj = t & 15, pp = t >> 4;
      const float4* D = (const float4*)v_lds;
      float4 ps = make_float4(0.f, 0.f, 0.f, 0.f);
#pragma unroll
      for (int c = 0; c < 16; ++c) {
        float4 q = D[jj * 257 + pp * 16 + c];
        ps.x += q.x; ps.y += q.y; ps.z += q.z; ps.w += q.w;
      }
      red2[jj * 16 + pp] = ps;
    }
    __syncthreads();
    if (t < 16) {
      float4 a = make_float4(0.f, 0.f, 0.f, 0.f);
#pragma unroll
      for (int p = 0; p < 16; ++p) {
        float4 r = red2[t * 16 + p];
        a.x += r.x; a.y += r.y; a.z += r.z; a.w += r.w;
      }
      int m = base0 + t;
      float4 res;
      res.x = beta[0 * NN + m] / a.x;
      res.y = beta[1 * NN + m] / a.y;
      res.z = beta[2 * NN + m] / a.z;
      res.w = beta[3 * NN + m] / a.w;
      astore2(v_t + m * 4, res.x, res.y);
      astore2(v_t + m * 4 + 2, res.z, res.w);
      if (it == NITER - 1) {
        out[4 * NN + 0 * NN + m] = eps * __logf(res.x);
        out[4 * NN + 1 * NN + m] = eps * __logf(res.y);
        out[4 * NN + 2 * NN + m] = eps * __logf(res.z);
        out[4 * NN + 3 * NN + m] = eps * __logf(res.w);
      }
    }
    if (it < NITER - 1) light_barrier(ctrs, 3 + 2 * it);   // v at IC
  }
}

// ---------------------------------------------------------------------------
extern "C" void kernel_launch(void* const* d_in, const int* in_sizes, int n_in,
                              void* d_out, int out_size, void* d_ws, size_t ws_size,
                              hipStream_t stream) {
  (void)in_sizes; (void)n_in; (void)out_size; (void)ws_size;
  const float* alpha = (const float*)d_in[0];   // f32 (4,4096)
  const float* beta  = (const float*)d_in[1];   // f32 (4,4096)
  const float* C     = (const float*)d_in[2];   // f32 (4096,4096)
  const void*  epsp  = d_in[3];                 // f32 scalar

  char* ws = (char*)d_ws;
  unsigned short* K  = (unsigned short*)ws;                      // 32 MiB
  float* u_t         = (float*)(ws + 33554432);                  // 64 KiB
  float* v_t         = (float*)(ws + 33554432 + 65536);          // 64 KiB
  unsigned int* ctrs = (unsigned int*)(ws + 33554432 + 131072);  // 96 B
  float* out = (float*)d_out;

  zero_ctrs<<<1, 64, 0, stream>>>(ctrs);
  sinkhorn_all<<<NBLK, 256, 0, stream>>>(alpha, beta, C, epsp, K, u_t, v_t,
                                         ctrs, out);
}

// Round 7
// 449.845 us; speedup vs baseline: 1.8437x; 1.2270x over previous
//
#include <hip/hip_runtime.h>
#include <stdint.h>

#define NN 4096
#define NITER 10
#define ROWS 16
#define NBLK 256

static __device__ __forceinline__ unsigned short f2bf(float f) {
  union { float f; unsigned int i; } x; x.f = f;
  unsigned int i = x.i;
  i += 0x7FFFu + ((i >> 16) & 1u);   // round-to-nearest-even
  return (unsigned short)(i >> 16);
}
static __device__ __forceinline__ unsigned int pk2(float a, float b) {
  return (unsigned int)f2bf(a) | ((unsigned int)f2bf(b) << 16);
}
static __device__ __forceinline__ float2 unpk(unsigned int u) {
  union { unsigned int i; float f; } a, b;
  a.i = u << 16; b.i = u & 0xFFFF0000u;
  return make_float2(a.f, b.f);
}
static __device__ __forceinline__ float read_eps(const void* p) {
  float f = *(const float*)p;
  if (f > 1e-4f && f < 1.0f) return f;
  union { unsigned int i; float f; } x;
  x.i = ((unsigned int)*(const unsigned short*)p) << 16;
  return x.f;
}

// --- IC-coherent (agent-scope, cache-bypassing) exchange helpers ----------
static __device__ __forceinline__ float2 aload2(const float* p) {
  unsigned long long q = __hip_atomic_load((const unsigned long long*)p,
      __ATOMIC_RELAXED, __HIP_MEMORY_SCOPE_AGENT);
  union { unsigned long long q; float2 f; } u; u.q = q; return u.f;
}
static __device__ __forceinline__ void astore2(float* p, float a, float b) {
  union { unsigned long long q; float2 f; } u; u.f = make_float2(a, b);
  __hip_atomic_store((unsigned long long*)p, u.q, __ATOMIC_RELAXED,
                     __HIP_MEMORY_SCOPE_AGENT);
}
static __device__ __forceinline__ void astore1(float* p, float v) {
  __hip_atomic_store(p, v, __ATOMIC_RELAXED, __HIP_MEMORY_SCOPE_AGENT);
}

// ws poisoned 0xAA pre-launch -> zero barrier state in a stream-ordered launch.
// flags: 256 slots at 16-uint (64 B) stride; xcd_done: 8 slots at 64 B stride.
__global__ __launch_bounds__(256) void zero_flags(unsigned int* __restrict__ c) {
#pragma unroll
  for (int k = 0; k < 17; ++k) c[threadIdx.x + k * 256] = 0;
}

// Hierarchical contention-free grid barrier:
//   arrive: each block STOREs token to its own 64B-strided flag (no RMW).
//   gather: leader blocks 0..7 poll their 32 members lane-parallel, then
//           store xcd_done[leader]. all blocks poll the 8 leader flags.
// Tokens strictly increase -> no flag reset races. 'heavy' adds the one-time
// agent release/acquire (K handoff); light barriers have NO cache fences
// (all iteration data crosses via agent-scope atomics served at the IC).
static __device__ __forceinline__ void grid_barrier(
    unsigned int* flags, unsigned int* xcd_done, int b, unsigned token,
    bool heavy) {
  __syncthreads();   // per-wave vmcnt drained -> all prior stores complete
  const int t = threadIdx.x;
  if (heavy && t == 0) __builtin_amdgcn_fence(__ATOMIC_RELEASE, "agent");
  if (t == 0)
    __hip_atomic_store(flags + b * 16, token, __ATOMIC_RELAXED,
                       __HIP_MEMORY_SCOPE_AGENT);
  if (b < 8 && t < 64) {           // leader: wave 0 gathers 32 members
    unsigned int* p = flags + (b + 8 * (t & 31)) * 16;
    for (;;) {
      unsigned v = (t < 32)
          ? __hip_atomic_load(p, __ATOMIC_RELAXED, __HIP_MEMORY_SCOPE_AGENT)
          : token;
      if (__ballot(v >= token) == 0xFFFFFFFFFFFFFFFFull) break;
      __builtin_amdgcn_s_sleep(1);
    }
    if (t == 0)
      __hip_atomic_store(xcd_done + b * 16, token, __ATOMIC_RELAXED,
                         __HIP_MEMORY_SCOPE_AGENT);
  }
  if (t < 64) {                    // everyone: wave 0 polls 8 leader flags
    unsigned int* q = xcd_done + (t & 7) * 16;
    for (;;) {
      unsigned v = (t < 8)
          ? __hip_atomic_load(q, __ATOMIC_RELAXED, __HIP_MEMORY_SCOPE_AGENT)
          : token;
      if (__ballot(v >= token) == 0xFFFFFFFFFFFFFFFFull) break;
      __builtin_amdgcn_s_sleep(2);
    }
  }
  if (heavy && t == 0) __builtin_amdgcn_fence(__ATOMIC_ACQUIRE, "agent");
  __syncthreads();
}

// ---------------------------------------------------------------------------
// Persistent kernel, XCD-banded ownership: own = ((b&7)<<5)|(b>>3) so each
// XCD's 32 blocks own contiguous 512-row and 512-col bands.
// Build + iteration-0 phase A are fused (v0 == 1, needs only OWN K rows) ->
// the single heavy (fenced) barrier is the u1-publish / K handoff.
__global__ __launch_bounds__(256, 1) void sinkhorn_all(
    const float* __restrict__ alpha, const float* __restrict__ beta,
    const float* __restrict__ C, const void* __restrict__ epsp,
    unsigned short* __restrict__ K, float* __restrict__ u_t,
    float* __restrict__ v_t, unsigned int* __restrict__ flags,
    unsigned int* __restrict__ xcd_done, float* __restrict__ out) {
  __shared__ float v_lds[4112 * 4];   // 64.25 KB staging / dump (stride 257)
  __shared__ float4 red2[256];
  const int t = threadIdx.x, b = blockIdx.x;
  const int wave = t >> 6, lane = t & 63, sw = lane & 7;
  const int own = ((b & 7) << 5) | (b >> 3);
  const int base0 = own * ROWS;               // first owned row AND col
  const float eps = read_eps(epsp);
  const float nie = -1.0f / eps;
  unsigned tok = 0;

  // ---- build own 16 K rows (no barrier needed before phase A of iter 0) ----
#pragma unroll 2
  for (int r = 0; r < ROWS; ++r) {
    const float4* Crow = (const float4*)(C + (size_t)(base0 + r) * NN) + t * 4;
    float4 c0 = Crow[0], c1 = Crow[1], c2 = Crow[2], c3 = Crow[3];
    uint4 k0, k1;
    k0.x = pk2(__expf(c0.x * nie), __expf(c0.y * nie));
    k0.y = pk2(__expf(c0.z * nie), __expf(c0.w * nie));
    k0.z = pk2(__expf(c1.x * nie), __expf(c1.y * nie));
    k0.w = pk2(__expf(c1.z * nie), __expf(c1.w * nie));
    k1.x = pk2(__expf(c2.x * nie), __expf(c2.y * nie));
    k1.y = pk2(__expf(c2.z * nie), __expf(c2.w * nie));
    k1.z = pk2(__expf(c3.x * nie), __expf(c3.y * nie));
    k1.w = pk2(__expf(c3.z * nie), __expf(c3.w * nie));
    uint4* Krow = (uint4*)(K + (size_t)(base0 + r) * NN);
    Krow[t * 2] = k0;
    Krow[t * 2 + 1] = k1;
  }

  for (int it = 0; it < NITER; ++it) {
    // ========== phase A: u[n] = alpha[n]/(K v)[n], own 16 rows ==========
    {
      float4* L = (float4*)v_lds;
      if (it == 0) {
#pragma unroll 4
        for (int k = 0; k < 16; ++k)
          L[t + k * 256] = make_float4(1.f, 1.f, 1.f, 1.f);   // v0 == 1
      } else {
#pragma unroll 4
        for (int k = 0; k < 16; ++k) {
          int slot = t + k * 256;
          float2 q0 = aload2(v_t + slot * 4);
          float2 q1 = aload2(v_t + slot * 4 + 2);
          L[slot ^ ((slot >> 3) & 7)] = make_float4(q0.x, q0.y, q1.x, q1.y);
        }
      }
    }
    __syncthreads();
    const int r0 = base0 + wave * 4;
    const uint4* Kr0 = (const uint4*)(K + (size_t)r0 * NN);
    uint4 karr[32];   // full prefetch: 32 outstanding 16-B loads per lane
#pragma unroll
    for (int mb = 0; mb < 8; ++mb) {
      int base = mb * 64 + lane;
      karr[mb * 4 + 0] = Kr0[base];
      karr[mb * 4 + 1] = Kr0[base + 512];
      karr[mb * 4 + 2] = Kr0[base + 1024];
      karr[mb * 4 + 3] = Kr0[base + 1536];
    }
    float acc[4][4] = {};
    const float4* VL = (const float4*)v_lds;
#pragma unroll
    for (int mb = 0; mb < 8; ++mb) {
      int m0 = mb * 512 + lane * 8;
      float4 vv[8];
#pragma unroll
      for (int j = 0; j < 8; ++j) vv[j] = VL[m0 + (j ^ sw)];  // vv[j]=col m0+j
#pragma unroll
      for (int r = 0; r < 4; ++r) {
        unsigned int cw[4] = {karr[mb*4+r].x, karr[mb*4+r].y,
                              karr[mb*4+r].z, karr[mb*4+r].w};
#pragma unroll
        for (int w = 0; w < 4; ++w) {
          float2 f = unpk(cw[w]);
          float4 va = vv[2 * w], vb = vv[2 * w + 1];
          acc[r][0] += f.x * va.x; acc[r][1] += f.x * va.y;
          acc[r][2] += f.x * va.z; acc[r][3] += f.x * va.w;
          acc[r][0] += f.y * vb.x; acc[r][1] += f.y * vb.y;
          acc[r][2] += f.y * vb.z; acc[r][3] += f.y * vb.w;
        }
      }
    }
#pragma unroll
    for (int off = 32; off > 0; off >>= 1)
#pragma unroll
      for (int r = 0; r < 4; ++r)
#pragma unroll
        for (int s = 0; s < 4; ++s)
          acc[r][s] += __shfl_xor(acc[r][s], off);
    if (lane < 16) {
      int rl = lane >> 2, s = lane & 3;
      int row = r0 + rl;
      float uval = alpha[s * NN + row] / acc[rl][s];
      astore1(u_t + row * 4 + s, uval);
      if (it == NITER - 1) out[s * NN + row] = eps * __logf(uval);
    }
    // iter-0 barrier is the heavy K handoff (release->IC, acquire-inv L2s)
    grid_barrier(flags, xcd_done, b, ++tok, it == 0);

    // ========== phase B: v[m] = beta[m]/(K^T u)[m], own 16 cols ==========
    {
      float4* L = (float4*)v_lds;
#pragma unroll 4
      for (int k = 0; k < 16; ++k) {
        int slot = t + k * 256;
        float2 q0 = aload2(u_t + slot * 4);
        float2 q1 = aload2(u_t + slot * 4 + 2);
        L[slot] = make_float4(q0.x, q0.y, q1.x, q1.y);   // linear slots
      }
    }
    __syncthreads();
    uint4 ka[16], kb[16];   // full prefetch of the 16-col strips
#pragma unroll
    for (int i = 0; i < 16; ++i) {
      int n = i * 256 + t;
      const uint4* kp = (const uint4*)(K + (size_t)n * NN + base0);
      ka[i] = kp[0]; kb[i] = kp[1];
    }
    float a2[16][4] = {};
#pragma unroll
    for (int i = 0; i < 16; ++i) {
      float4 u4 = ((const float4*)v_lds)[i * 256 + t];
      unsigned int aw[4] = {ka[i].x, ka[i].y, ka[i].z, ka[i].w};
      unsigned int bw[4] = {kb[i].x, kb[i].y, kb[i].z, kb[i].w};
#pragma unroll
      for (int w = 0; w < 4; ++w) {
        float2 fa = unpk(aw[w]);
        a2[2*w][0]   += fa.x * u4.x; a2[2*w][1]   += fa.x * u4.y;
        a2[2*w][2]   += fa.x * u4.z; a2[2*w][3]   += fa.x * u4.w;
        a2[2*w+1][0] += fa.y * u4.x; a2[2*w+1][1] += fa.y * u4.y;
        a2[2*w+1][2] += fa.y * u4.z; a2[2*w+1][3] += fa.y * u4.w;
        float2 fb = unpk(bw[w]);
        a2[8+2*w][0] += fb.x * u4.x; a2[8+2*w][1] += fb.x * u4.y;
        a2[8+2*w][2] += fb.x * u4.z; a2[8+2*w][3] += fb.x * u4.w;
        a2[9+2*w][0] += fb.y * u4.x; a2[9+2*w][1] += fb.y * u4.y;
        a2[9+2*w][2] += fb.y * u4.z; a2[9+2*w][3] += fb.y * u4.w;
      }
    }
    __syncthreads();   // u reads done; reuse v_lds for the dump
    {
      float4* D = (float4*)v_lds;
#pragma unroll
      for (int j = 0; j < 16; ++j)   // stride 257: conflict-free
        D[j * 257 + t] = make_float4(a2[j][0], a2[j][1], a2[j][2], a2[j][3]);
    }
    __syncthreads();
    {
      int jj = t & 15, pp = t >> 4;
      const float4* D = (const float4*)v_lds;
      float4 ps = make_float4(0.f, 0.f, 0.f, 0.f);
#pragma unroll
      for (int c = 0; c < 16; ++c) {
        float4 q = D[jj * 257 + pp * 16 + c];
        ps.x += q.x; ps.y += q.y; ps.z += q.z; ps.w += q.w;
      }
      red2[jj * 16 + pp] = ps;
    }
    __syncthreads();
    if (t < 16) {
      float4 a = make_float4(0.f, 0.f, 0.f, 0.f);
#pragma unroll
      for (int p = 0; p < 16; ++p) {
        float4 r = red2[t * 16 + p];
        a.x += r.x; a.y += r.y; a.z += r.z; a.w += r.w;
      }
      int m = base0 + t;
      float4 res;
      res.x = beta[0 * NN + m] / a.x;
      res.y = beta[1 * NN + m] / a.y;
      res.z = beta[2 * NN + m] / a.z;
      res.w = beta[3 * NN + m] / a.w;
      astore2(v_t + m * 4, res.x, res.y);
      astore2(v_t + m * 4 + 2, res.z, res.w);
      if (it == NITER - 1) {
        out[4 * NN + 0 * NN + m] = eps * __logf(res.x);
        out[4 * NN + 1 * NN + m] = eps * __logf(res.y);
        out[4 * NN + 2 * NN + m] = eps * __logf(res.z);
        out[4 * NN + 3 * NN + m] = eps * __logf(res.w);
      }
    }
    if (it < NITER - 1) grid_barrier(flags, xcd_done, b, ++tok, false);
  }
}

// ---------------------------------------------------------------------------
extern "C" void kernel_launch(void* const* d_in, const int* in_sizes, int n_in,
                              void* d_out, int out_size, void* d_ws, size_t ws_size,
                              hipStream_t stream) {
  (void)in_sizes; (void)n_in; (void)out_size; (void)ws_size;
  const float* alpha = (const float*)d_in[0];   // f32 (4,4096)
  const float* beta  = (const float*)d_in[1];   // f32 (4,4096)
  const float* C     = (const float*)d_in[2];   // f32 (4096,4096)
  const void*  epsp  = d_in[3];                 // f32 scalar

  char* ws = (char*)d_ws;
  unsigned short* K      = (unsigned short*)ws;                      // 32 MiB
  float* u_t             = (float*)(ws + 33554432);                  // 64 KiB
  float* v_t             = (float*)(ws + 33554432 + 65536);          // 64 KiB
  unsigned int* flags    = (unsigned int*)(ws + 33554432 + 131072);  // 16 KiB
  unsigned int* xcd_done = (unsigned int*)(ws + 33554432 + 131072 + 16384);
  float* out = (float*)d_out;

  zero_flags<<<1, 256, 0, stream>>>(flags);   // zeros flags + xcd_done (17*256)
  sinkhorn_all<<<NBLK, 256, 0, stream>>>(alpha, beta, C, epsp, K, u_t, v_t,
                                         flags, xcd_done, out);
}

// Round 8
// 330.736 us; speedup vs baseline: 2.5076x; 1.3601x over previous
//
#include <hip/hip_runtime.h>
#include <stdint.h>

#define NN 4096
#define NITER 10
#define ROWS 16
#define NBLK 256

// LDS map (bytes): KT strip [0,139264) | stage 16640 | red 4096  = 160,000
#define KT_COL   8704      // per-col stride: 32 chunks x 272
#define KT_CHK   272       // 128 rows bf16 (256 B) + 16 pad
#define STG_OFF  139264
#define RED_OFF  155904

static __device__ __forceinline__ unsigned short f2bf(float f) {
  union { float f; unsigned int i; } x; x.f = f;
  unsigned int i = x.i;
  i += 0x7FFFu + ((i >> 16) & 1u);
  return (unsigned short)(i >> 16);
}
static __device__ __forceinline__ unsigned int pk2(float a, float b) {
  return (unsigned int)f2bf(a) | ((unsigned int)f2bf(b) << 16);
}
static __device__ __forceinline__ float2 unpk(unsigned int u) {
  union { unsigned int i; float f; } a, b;
  a.i = u << 16; b.i = u & 0xFFFF0000u;
  return make_float2(a.f, b.f);
}
static __device__ __forceinline__ float read_eps(const void* p) {
  float f = *(const float*)p;
  if (f > 1e-4f && f < 1.0f) return f;
  union { unsigned int i; float f; } x;
  x.i = ((unsigned int)*(const unsigned short*)p) << 16;
  return x.f;
}
static __device__ __forceinline__ unsigned long long aload8(const unsigned long long* p) {
  return __hip_atomic_load(p, __ATOMIC_RELAXED, __HIP_MEMORY_SCOPE_AGENT);
}
static __device__ __forceinline__ void astore8(unsigned long long* p, unsigned long long v) {
  __hip_atomic_store(p, v, __ATOMIC_RELAXED, __HIP_MEMORY_SCOPE_AGENT);
}

__global__ __launch_bounds__(256) void zero_flags(unsigned int* __restrict__ c) {
#pragma unroll
  for (int k = 0; k < 16; ++k) c[threadIdx.x + k * 256] = 0;
}

// Single-level contention-free barrier: block b stores token to flags[b*16];
// thread t polls flags[t*16]. Loads only (no RMW), 64-B strided, no fences.
static __device__ __forceinline__ void grid_barrier(
    unsigned int* flags, int b, unsigned token) {
  __syncthreads();
  if (threadIdx.x == 0)
    __hip_atomic_store(flags + b * 16, token, __ATOMIC_RELAXED,
                       __HIP_MEMORY_SCOPE_AGENT);
  const unsigned int* p = flags + threadIdx.x * 16;
  for (;;) {
    unsigned v = __hip_atomic_load(p, __ATOMIC_RELAXED,
                                   __HIP_MEMORY_SCOPE_AGENT);
    if (__ballot(v >= token) == 0xFFFFFFFFFFFFFFFFull) break;
    __builtin_amdgcn_s_sleep(2);
  }
  __syncthreads();
}

// ---------------------------------------------------------------------------
// Persistent: block b owns rows [16b,+16) and cols [16b,+16) (banded across
// XCDs). Row-K: global, PRIVATE to the block -> stays L2-resident, no fences.
// Col-K^T: LDS-resident for all 10 iterations. u/v cross via bf16x4 IC atomics.
__global__ __launch_bounds__(256, 1) void sinkhorn_all(
    const float* __restrict__ alpha, const float* __restrict__ beta,
    const float* __restrict__ C, const void* __restrict__ epsp,
    unsigned short* __restrict__ K, unsigned long long* __restrict__ u_bf,
    unsigned long long* __restrict__ v_bf, unsigned int* __restrict__ flags,
    float* __restrict__ out) {
  __shared__ float4 smem4[10000];            // 160,000 B
  char* sm = (char*)smem4;
  const int t = threadIdx.x, b = blockIdx.x;
  const int wave = t >> 6, lane = t & 63, sw = lane & 7;
  const int own = ((b & 7) << 5) | (b >> 3);
  const int base0 = own * ROWS;              // first owned row AND col
  const float eps = read_eps(epsp);
  const float nie = -1.0f / eps;
  unsigned tok = 0;

  // ---- build row-K (global, private): coalesced C row reads ----
#pragma unroll 2
  for (int r = 0; r < ROWS; ++r) {
    const float4* Crow = (const float4*)(C + (size_t)(base0 + r) * NN) + t * 4;
    float4 c0 = Crow[0], c1 = Crow[1], c2 = Crow[2], c3 = Crow[3];
    uint4 k0, k1;
    k0.x = pk2(__expf(c0.x * nie), __expf(c0.y * nie));
    k0.y = pk2(__expf(c0.z * nie), __expf(c0.w * nie));
    k0.z = pk2(__expf(c1.x * nie), __expf(c1.y * nie));
    k0.w = pk2(__expf(c1.z * nie), __expf(c1.w * nie));
    k1.x = pk2(__expf(c2.x * nie), __expf(c2.y * nie));
    k1.y = pk2(__expf(c2.z * nie), __expf(c2.w * nie));
    k1.z = pk2(__expf(c3.x * nie), __expf(c3.y * nie));
    k1.w = pk2(__expf(c3.z * nie), __expf(c3.w * nie));
    uint4* Krow = (uint4*)(K + (size_t)(base0 + r) * NN);
    Krow[t * 2] = k0;
    Krow[t * 2 + 1] = k1;
  }

  // ---- build K^T strip in LDS from strided C column reads ----
  {
    const int p = t & 3;          // 16-B col subgroup (4 cols)
    const int rb = t >> 2;        // row-within-64
    const int cb = p * 4;         // local col base
#pragma unroll 1
    for (int q = 0; q < 64; q += 8) {
      float4 cv[8];
#pragma unroll
      for (int z = 0; z < 8; ++z)
        cv[z] = *(const float4*)(C + (size_t)((q + z) * 64 + rb) * NN + base0 + cb);
#pragma unroll
      for (int z = 0; z < 8; ++z) {
        int n = (q + z) * 64 + rb;
        int ba = (n >> 7) * KT_CHK + (n & 127) * 2;
        *(unsigned short*)(sm + (cb + 0) * KT_COL + ba) = f2bf(__expf(cv[z].x * nie));
        *(unsigned short*)(sm + (cb + 1) * KT_COL + ba) = f2bf(__expf(cv[z].y * nie));
        *(unsigned short*)(sm + (cb + 2) * KT_COL + ba) = f2bf(__expf(cv[z].z * nie));
        *(unsigned short*)(sm + (cb + 3) * KT_COL + ba) = f2bf(__expf(cv[z].w * nie));
      }
    }
  }
  // no barrier: all K data is block-private. First cross-block data is u.

  for (int it = 0; it < NITER; ++it) {
    // ========== phase A: u[n] = alpha[n]/(K v)[n], own 16 rows ==========
    float acc[4][4] = {};
    const int r0 = base0 + wave * 4;
    const uint4* Kr0 = (const uint4*)(K + (size_t)r0 * NN);
#pragma unroll 1
    for (int q = 0; q < 4; ++q) {            // quarter m-stages (1024 m each)
      {
        float4* L = (float4*)(sm + STG_OFF);
        if (it == 0) {
#pragma unroll
          for (int jj = 0; jj < 4; ++jj)
            L[t + jj * 256] = make_float4(1.f, 1.f, 1.f, 1.f);
        } else {
#pragma unroll
          for (int jj = 0; jj < 4; ++jj) {
            int slot = t + jj * 256;
            unsigned long long ub = aload8(v_bf + q * 1024 + slot);
            float2 lo = unpk((unsigned)ub);
            float2 hi = unpk((unsigned)(ub >> 32));
            L[slot ^ ((slot >> 3) & 7)] = make_float4(lo.x, lo.y, hi.x, hi.y);
          }
        }
      }
      __syncthreads();
      uint4 karr[8];
#pragma unroll
      for (int ms = 0; ms < 2; ++ms) {
        int moff = q * 128 + ms * 64 + lane;
        karr[ms * 4 + 0] = Kr0[moff];
        karr[ms * 4 + 1] = Kr0[moff + 512];
        karr[ms * 4 + 2] = Kr0[moff + 1024];
        karr[ms * 4 + 3] = Kr0[moff + 1536];
      }
      const float4* VL = (const float4*)(sm + STG_OFF);
#pragma unroll
      for (int ms = 0; ms < 2; ++ms) {
        int mb = ms * 512 + lane * 8;        // slot-space within quarter
        float4 vv[8];
#pragma unroll
        for (int j = 0; j < 8; ++j) vv[j] = VL[mb + (j ^ sw)];
#pragma unroll
        for (int r = 0; r < 4; ++r) {
          unsigned int cw[4] = {karr[ms*4+r].x, karr[ms*4+r].y,
                                karr[ms*4+r].z, karr[ms*4+r].w};
#pragma unroll
          for (int w = 0; w < 4; ++w) {
            float2 f = unpk(cw[w]);
            float4 va = vv[2 * w], vb = vv[2 * w + 1];
            acc[r][0] += f.x * va.x; acc[r][1] += f.x * va.y;
            acc[r][2] += f.x * va.z; acc[r][3] += f.x * va.w;
            acc[r][0] += f.y * vb.x; acc[r][1] += f.y * vb.y;
            acc[r][2] += f.y * vb.z; acc[r][3] += f.y * vb.w;
          }
        }
      }
      __syncthreads();
    }
#pragma unroll
    for (int off = 32; off > 0; off >>= 1)
#pragma unroll
      for (int r = 0; r < 4; ++r)
#pragma unroll
        for (int s = 0; s < 4; ++s)
          acc[r][s] += __shfl_xor(acc[r][s], off);
    if (lane < 4) {
      int row = r0 + lane;
      float ux = alpha[0 * NN + row] / acc[lane][0];
      float uy = alpha[1 * NN + row] / acc[lane][1];
      float uz = alpha[2 * NN + row] / acc[lane][2];
      float uw = alpha[3 * NN + row] / acc[lane][3];
      unsigned long long ub = (unsigned long long)pk2(ux, uy) |
                              ((unsigned long long)pk2(uz, uw) << 32);
      astore8(u_bf + row, ub);
      if (it == NITER - 1) {
        out[0 * NN + row] = eps * __logf(ux);
        out[1 * NN + row] = eps * __logf(uy);
        out[2 * NN + row] = eps * __logf(uz);
        out[3 * NN + row] = eps * __logf(uw);
      }
    }
    grid_barrier(flags, b, ++tok);           // u published (IC)

    // ========== phase B: v[m] = beta[m]/(K^T u)[m], own 16 cols ==========
    float4 bacc = make_float4(0.f, 0.f, 0.f, 0.f);
    const int c = t & 15, k = t >> 4;
#pragma unroll 1
    for (int q = 0; q < 4; ++q) {            // quarter n-stages
      {
        float* US = (float*)(sm + STG_OFF);
#pragma unroll
        for (int jj = 0; jj < 4; ++jj) {
          int nloc = t + jj * 256;
          unsigned long long ub = aload8(u_bf + q * 1024 + nloc);
          float2 lo = unpk((unsigned)ub);
          float2 hi = unpk((unsigned)(ub >> 32));
          *(float4*)(US + nloc * 4 + (nloc >> 6) * 4) =
              make_float4(lo.x, lo.y, hi.x, hi.y);
        }
      }
      __syncthreads();
      const float* US = (const float*)(sm + STG_OFF);
#pragma unroll
      for (int i = 0; i < 8; ++i) {
        int nb = k * 64 + i * 8;             // local row base within quarter
        const uint4 kt = *(const uint4*)(
            sm + c * KT_COL + ((q * 1024 + nb) >> 7) * KT_CHK + (nb & 127) * 2);
        unsigned int kw[4] = {kt.x, kt.y, kt.z, kt.w};
#pragma unroll
        for (int w = 0; w < 4; ++w) {
          float2 f = unpk(kw[w]);
          int j0 = nb + 2 * w, j1 = nb + 2 * w + 1;
          float4 u0 = *(const float4*)(US + j0 * 4 + (j0 >> 6) * 4);
          float4 u1 = *(const float4*)(US + j1 * 4 + (j1 >> 6) * 4);
          bacc.x += f.x * u0.x; bacc.y += f.x * u0.y;
          bacc.z += f.x * u0.z; bacc.w += f.x * u0.w;
          bacc.x += f.y * u1.x; bacc.y += f.y * u1.y;
          bacc.z += f.y * u1.z; bacc.w += f.y * u1.w;
        }
      }
      __syncthreads();
    }
    {
      float4* red = (float4*)(sm + RED_OFF);
      red[k * 16 + c] = bacc;
    }
    __syncthreads();
    if (t < 16) {
      const float4* red = (const float4*)(sm + RED_OFF);
      float4 a = make_float4(0.f, 0.f, 0.f, 0.f);
#pragma unroll
      for (int k2 = 0; k2 < 16; ++k2) {
        float4 r = red[k2 * 16 + t];
        a.x += r.x; a.y += r.y; a.z += r.z; a.w += r.w;
      }
      int m = base0 + t;
      float vx = beta[0 * NN + m] / a.x;
      float vy = beta[1 * NN + m] / a.y;
      float vz = beta[2 * NN + m] / a.z;
      float vw = beta[3 * NN + m] / a.w;
      unsigned long long vb = (unsigned long long)pk2(vx, vy) |
                              ((unsigned long long)pk2(vz, vw) << 32);
      astore8(v_bf + m, vb);
      if (it == NITER - 1) {
        out[4 * NN + 0 * NN + m] = eps * __logf(vx);
        out[4 * NN + 1 * NN + m] = eps * __logf(vy);
        out[4 * NN + 2 * NN + m] = eps * __logf(vz);
        out[4 * NN + 3 * NN + m] = eps * __logf(vw);
      }
    }
    if (it < NITER - 1) grid_barrier(flags, b, ++tok);   // v published (IC)
  }
}

// ---------------------------------------------------------------------------
extern "C" void kernel_launch(void* const* d_in, const int* in_sizes, int n_in,
                              void* d_out, int out_size, void* d_ws, size_t ws_size,
                              hipStream_t stream) {
  (void)in_sizes; (void)n_in; (void)out_size; (void)ws_size;
  const float* alpha = (const float*)d_in[0];   // f32 (4,4096)
  const float* beta  = (const float*)d_in[1];   // f32 (4,4096)
  const float* C     = (const float*)d_in[2];   // f32 (4096,4096)
  const void*  epsp  = d_in[3];                 // f32 scalar

  char* ws = (char*)d_ws;
  unsigned short* K        = (unsigned short*)ws;                 // 32 MiB
  unsigned long long* u_bf = (unsigned long long*)(ws + 33554432);        // 32 KiB
  unsigned long long* v_bf = (unsigned long long*)(ws + 33554432 + 32768);// 32 KiB
  unsigned int* flags      = (unsigned int*)(ws + 33554432 + 65536);      // 16 KiB
  float* out = (float*)d_out;

  zero_flags<<<1, 256, 0, stream>>>(flags);
  sinkhorn_all<<<NBLK, 256, 0, stream>>>(alpha, beta, C, epsp, K, u_bf, v_bf,
                                         flags, out);
}

// Round 9
// 268.045 us; speedup vs baseline: 3.0941x; 1.2339x over previous
//
#include <hip/hip_runtime.h>
#include <stdint.h>

#define NN 4096
#define NITER 10
#define ROWS 16
#define NBLK 256

// LDS (bytes): KT interleaved [0,131072) | stage 16640 | red 4096 = 151,808
#define STG_OFF  131072
#define RED_OFF  147712

static __device__ __forceinline__ unsigned short f2bf(float f) {
  union { float f; unsigned int i; } x; x.f = f;
  unsigned int i = x.i;
  i += 0x7FFFu + ((i >> 16) & 1u);
  return (unsigned short)(i >> 16);
}
static __device__ __forceinline__ unsigned int pk2(float a, float b) {
  return (unsigned int)f2bf(a) | ((unsigned int)f2bf(b) << 16);
}
static __device__ __forceinline__ float2 unpk(unsigned int u) {
  union { unsigned int i; float f; } a, b;
  a.i = u << 16; b.i = u & 0xFFFF0000u;
  return make_float2(a.f, b.f);
}
static __device__ __forceinline__ float read_eps(const void* p) {
  float f = *(const float*)p;
  if (f > 1e-4f && f < 1.0f) return f;
  union { unsigned int i; float f; } x;
  x.i = ((unsigned int)*(const unsigned short*)p) << 16;
  return x.f;
}
static __device__ __forceinline__ void astore8(unsigned long long* p, unsigned long long v) {
  __hip_atomic_store(p, v, __ATOMIC_RELAXED, __HIP_MEMORY_SCOPE_AGENT);
}
// unpack one bf16x4 (2 words) into float4
static __device__ __forceinline__ float4 up4(unsigned int w0, unsigned int w1) {
  float2 a = unpk(w0), b = unpk(w1);
  return make_float4(a.x, a.y, b.x, b.y);
}

__global__ __launch_bounds__(256) void zero_flags(unsigned int* __restrict__ c) {
#pragma unroll
  for (int k = 0; k < 16; ++k) c[threadIdx.x + k * 256] = 0;
}

// Contention-free barrier: block b stores token to flags[b*16] (no RMW);
// wave 0 polls, 4 flags per lane. No cache-maintenance fences anywhere.
static __device__ __forceinline__ void grid_barrier(
    unsigned int* flags, int b, unsigned token) {
  __syncthreads();
  const int t = threadIdx.x;
  if (t == 0)
    __hip_atomic_store(flags + b * 16, token, __ATOMIC_RELAXED,
                       __HIP_MEMORY_SCOPE_AGENT);
  if (t < 64) {
    for (;;) {
      unsigned a0 = __hip_atomic_load(flags + t * 16,          __ATOMIC_RELAXED, __HIP_MEMORY_SCOPE_AGENT);
      unsigned a1 = __hip_atomic_load(flags + (t + 64) * 16,   __ATOMIC_RELAXED, __HIP_MEMORY_SCOPE_AGENT);
      unsigned a2 = __hip_atomic_load(flags + (t + 128) * 16,  __ATOMIC_RELAXED, __HIP_MEMORY_SCOPE_AGENT);
      unsigned a3 = __hip_atomic_load(flags + (t + 192) * 16,  __ATOMIC_RELAXED, __HIP_MEMORY_SCOPE_AGENT);
      bool ok = a0 >= token && a1 >= token && a2 >= token && a3 >= token;
      if (__ballot(ok) == 0xFFFFFFFFFFFFFFFFull) break;
      __builtin_amdgcn_s_sleep(2);
    }
  }
  __syncthreads();
}

// ---------------------------------------------------------------------------
// Persistent: block b owns rows [16b,+16) and cols [16b,+16) (banded).
// Row-K: global, block-private -> L2-resident. Col-K^T: LDS, lane-linear
// interleave [(q*8+i)*256 + k*16 + c] (16-B units) -> conflict-free reads.
// u/v: bf16x4 epoch buffers (fresh address per iteration) -> writers publish
// with 8-B agent atomics (IC), readers use plain vectorized loads.
__global__ __launch_bounds__(256, 1) void sinkhorn_all(
    const float* __restrict__ alpha, const float* __restrict__ beta,
    const float* __restrict__ C, const void* __restrict__ epsp,
    unsigned short* __restrict__ K, unsigned long long* __restrict__ u_ep,
    unsigned long long* __restrict__ v_ep, unsigned int* __restrict__ flags,
    float* __restrict__ out) {
  __shared__ float4 smem4[9488];             // 151,808 B
  char* sm = (char*)smem4;
  const int t = threadIdx.x, b = blockIdx.x;
  const int wave = t >> 6, lane = t & 63, sw = lane & 7;
  const int own = ((b & 7) << 5) | (b >> 3);
  const int base0 = own * ROWS;              // first owned row AND col
  const float eps = read_eps(epsp);
  const float nie = -1.0f / eps;
  unsigned tok = 0;

  // ---- build row-K (global, private): coalesced C row reads ----
#pragma unroll 2
  for (int r = 0; r < ROWS; ++r) {
    const float4* Crow = (const float4*)(C + (size_t)(base0 + r) * NN) + t * 4;
    float4 c0 = Crow[0], c1 = Crow[1], c2 = Crow[2], c3 = Crow[3];
    uint4 k0, k1;
    k0.x = pk2(__expf(c0.x * nie), __expf(c0.y * nie));
    k0.y = pk2(__expf(c0.z * nie), __expf(c0.w * nie));
    k0.z = pk2(__expf(c1.x * nie), __expf(c1.y * nie));
    k0.w = pk2(__expf(c1.z * nie), __expf(c1.w * nie));
    k1.x = pk2(__expf(c2.x * nie), __expf(c2.y * nie));
    k1.y = pk2(__expf(c2.z * nie), __expf(c2.w * nie));
    k1.z = pk2(__expf(c3.x * nie), __expf(c3.y * nie));
    k1.w = pk2(__expf(c3.z * nie), __expf(c3.w * nie));
    uint4* Krow = (uint4*)(K + (size_t)(base0 + r) * NN);
    Krow[t * 2] = k0;
    Krow[t * 2 + 1] = k1;
  }

  // ---- build K^T strip in LDS (interleaved layout) ----
  {
    const int p = t & 3;          // 4-col subgroup
    const int rb = t >> 2;        // row-within-64
    const int cb = p * 4;
#pragma unroll 1
    for (int q = 0; q < 64; q += 8) {
      float4 cv[8];
#pragma unroll
      for (int z = 0; z < 8; ++z)
        cv[z] = *(const float4*)(C + (size_t)((q + z) * 64 + rb) * NN + base0 + cb);
#pragma unroll
      for (int z = 0; z < 8; ++z) {
        int n = (q + z) * 64 + rb;
        int u16 = ((n >> 10) * 8 + ((n >> 3) & 7)) * 256 + ((n >> 6) & 15) * 16;
        int jo = (n & 7) * 2;
        *(unsigned short*)(sm + (size_t)(u16 + cb + 0) * 16 + jo) = f2bf(__expf(cv[z].x * nie));
        *(unsigned short*)(sm + (size_t)(u16 + cb + 1) * 16 + jo) = f2bf(__expf(cv[z].y * nie));
        *(unsigned short*)(sm + (size_t)(u16 + cb + 2) * 16 + jo) = f2bf(__expf(cv[z].z * nie));
        *(unsigned short*)(sm + (size_t)(u16 + cb + 3) * 16 + jo) = f2bf(__expf(cv[z].w * nie));
      }
    }
  }
  // no barrier: all K data block-private; first cross-block data is u.

  for (int it = 0; it < NITER; ++it) {
    // ========== phase A: u[n] = alpha[n]/(K v)[n], own 16 rows ==========
    float acc[4][4] = {};
    const int r0 = base0 + wave * 4;
    const uint4* Kr0 = (const uint4*)(K + (size_t)r0 * NN);
    const uint4* VB = (const uint4*)(v_ep + (size_t)(it - 1) * NN);
    uint4 sv0, sv1;
    if (it > 0) { sv0 = VB[t * 2]; sv1 = VB[t * 2 + 1]; }
#pragma unroll 1
    for (int q = 0; q < 4; ++q) {
      {
        float4* L = (float4*)(sm + STG_OFF);
        int s0 = t * 4;
        if (it == 0) {
          float4 one = make_float4(1.f, 1.f, 1.f, 1.f);
#pragma unroll
          for (int e = 0; e < 4; ++e) {
            int s = s0 + e;
            L[s ^ ((s >> 3) & 7)] = one;
          }
        } else {
          float4 f0 = up4(sv0.x, sv0.y), f1 = up4(sv0.z, sv0.w);
          float4 f2 = up4(sv1.x, sv1.y), f3 = up4(sv1.z, sv1.w);
          L[(s0 + 0) ^ (((s0 + 0) >> 3) & 7)] = f0;
          L[(s0 + 1) ^ (((s0 + 1) >> 3) & 7)] = f1;
          L[(s0 + 2) ^ (((s0 + 2) >> 3) & 7)] = f2;
          L[(s0 + 3) ^ (((s0 + 3) >> 3) & 7)] = f3;
        }
      }
      __syncthreads();
      if (it > 0 && q < 3) {                 // prefetch next quarter's v
        sv0 = VB[(q + 1) * 512 + t * 2];
        sv1 = VB[(q + 1) * 512 + t * 2 + 1];
      }
      uint4 karr[8];
#pragma unroll
      for (int ms = 0; ms < 2; ++ms) {
        int moff = q * 128 + ms * 64 + lane;
        karr[ms * 4 + 0] = Kr0[moff];
        karr[ms * 4 + 1] = Kr0[moff + 512];
        karr[ms * 4 + 2] = Kr0[moff + 1024];
        karr[ms * 4 + 3] = Kr0[moff + 1536];
      }
      const float4* VL = (const float4*)(sm + STG_OFF);
#pragma unroll
      for (int ms = 0; ms < 2; ++ms) {
        int mb = ms * 512 + lane * 8;
        float4 vv[8];
#pragma unroll
        for (int j = 0; j < 8; ++j) vv[j] = VL[mb + (j ^ sw)];
#pragma unroll
        for (int r = 0; r < 4; ++r) {
          unsigned int cw[4] = {karr[ms*4+r].x, karr[ms*4+r].y,
                                karr[ms*4+r].z, karr[ms*4+r].w};
#pragma unroll
          for (int w = 0; w < 4; ++w) {
            float2 f = unpk(cw[w]);
            float4 va = vv[2 * w], vb = vv[2 * w + 1];
            acc[r][0] += f.x * va.x; acc[r][1] += f.x * va.y;
            acc[r][2] += f.x * va.z; acc[r][3] += f.x * va.w;
            acc[r][0] += f.y * vb.x; acc[r][1] += f.y * vb.y;
            acc[r][2] += f.y * vb.z; acc[r][3] += f.y * vb.w;
          }
        }
      }
      __syncthreads();
    }
#pragma unroll
    for (int off = 32; off > 0; off >>= 1)
#pragma unroll
      for (int r = 0; r < 4; ++r)
#pragma unroll
        for (int s = 0; s < 4; ++s)
          acc[r][s] += __shfl_xor(acc[r][s], off);
    if (lane < 4) {
      int row = r0 + lane;
      float ux = alpha[0 * NN + row] / acc[lane][0];
      float uy = alpha[1 * NN + row] / acc[lane][1];
      float uz = alpha[2 * NN + row] / acc[lane][2];
      float uw = alpha[3 * NN + row] / acc[lane][3];
      unsigned long long ub = (unsigned long long)pk2(ux, uy) |
                              ((unsigned long long)pk2(uz, uw) << 32);
      astore8(u_ep + (size_t)it * NN + row, ub);
      if (it == NITER - 1) {
        out[0 * NN + row] = eps * __logf(ux);
        out[1 * NN + row] = eps * __logf(uy);
        out[2 * NN + row] = eps * __logf(uz);
        out[3 * NN + row] = eps * __logf(uw);
      }
    }
    grid_barrier(flags, b, ++tok);           // u epoch published (IC)

    // ========== phase B: v[m] = beta[m]/(K^T u)[m], own 16 cols ==========
    float4 bacc = make_float4(0.f, 0.f, 0.f, 0.f);
    const uint4* UB = (const uint4*)(u_ep + (size_t)it * NN);
    uint4 su0 = UB[t * 2], su1 = UB[t * 2 + 1];
#pragma unroll 1
    for (int q = 0; q < 4; ++q) {
      {
        char* US = sm + STG_OFF;
        int n0 = t * 4;
        float4 f0 = up4(su0.x, su0.y), f1 = up4(su0.z, su0.w);
        float4 f2 = up4(su1.x, su1.y), f3 = up4(su1.z, su1.w);
        *(float4*)(US + (n0 + 0) * 16 + ((n0 + 0) >> 6) * 16) = f0;
        *(float4*)(US + (n0 + 1) * 16 + ((n0 + 1) >> 6) * 16) = f1;
        *(float4*)(US + (n0 + 2) * 16 + ((n0 + 2) >> 6) * 16) = f2;
        *(float4*)(US + (n0 + 3) * 16 + ((n0 + 3) >> 6) * 16) = f3;
      }
      __syncthreads();
      if (q < 3) {                           // prefetch next quarter's u
        su0 = UB[(q + 1) * 512 + t * 2];
        su1 = UB[(q + 1) * 512 + t * 2 + 1];
      }
      const char* US = sm + STG_OFF;
      const int k = t >> 4;
#pragma unroll
      for (int i = 0; i < 8; ++i) {
        uint4 kt = ((const uint4*)sm)[(q * 8 + i) * 256 + t];  // lane-linear
        int nb = k * 64 + i * 8;
        unsigned int kw[4] = {kt.x, kt.y, kt.z, kt.w};
#pragma unroll
        for (int w = 0; w < 4; ++w) {
          float2 f = unpk(kw[w]);
          int j0 = nb + 2 * w, j1 = nb + 2 * w + 1;
          float4 u0 = *(const float4*)(US + j0 * 16 + (j0 >> 6) * 16);
          float4 u1 = *(const float4*)(US + j1 * 16 + (j1 >> 6) * 16);
          bacc.x += f.x * u0.x; bacc.y += f.x * u0.y;
          bacc.z += f.x * u0.z; bacc.w += f.x * u0.w;
          bacc.x += f.y * u1.x; bacc.y += f.y * u1.y;
          bacc.z += f.y * u1.z; bacc.w += f.y * u1.w;
        }
      }
      __syncthreads();
    }
    {
      float4* red = (float4*)(sm + RED_OFF);
      red[(t >> 4) * 16 + (t & 15)] = bacc;
    }
    __syncthreads();
    if (t < 16) {
      const float4* red = (const float4*)(sm + RED_OFF);
      float4 a = make_float4(0.f, 0.f, 0.f, 0.f);
#pragma unroll
      for (int k2 = 0; k2 < 16; ++k2) {
        float4 r = red[k2 * 16 + t];
        a.x += r.x; a.y += r.y; a.z += r.z; a.w += r.w;
      }
      int m = base0 + t;
      float vx = beta[0 * NN + m] / a.x;
      float vy = beta[1 * NN + m] / a.y;
      float vz = beta[2 * NN + m] / a.z;
      float vw = beta[3 * NN + m] / a.w;
      unsigned long long vb = (unsigned long long)pk2(vx, vy) |
                              ((unsigned long long)pk2(vz, vw) << 32);
      astore8(v_ep + (size_t)it * NN + m, vb);
      if (it == NITER - 1) {
        out[4 * NN + 0 * NN + m] = eps * __logf(vx);
        out[4 * NN + 1 * NN + m] = eps * __logf(vy);
        out[4 * NN + 2 * NN + m] = eps * __logf(vz);
        out[4 * NN + 3 * NN + m] = eps * __logf(vw);
      }
    }
    if (it < NITER - 1) grid_barrier(flags, b, ++tok);   // v epoch published
  }
}

// ---------------------------------------------------------------------------
extern "C" void kernel_launch(void* const* d_in, const int* in_sizes, int n_in,
                              void* d_out, int out_size, void* d_ws, size_t ws_size,
                              hipStream_t stream) {
  (void)in_sizes; (void)n_in; (void)out_size; (void)ws_size;
  const float* alpha = (const float*)d_in[0];   // f32 (4,4096)
  const float* beta  = (const float*)d_in[1];   // f32 (4,4096)
  const float* C     = (const float*)d_in[2];   // f32 (4096,4096)
  const void*  epsp  = d_in[3];                 // f32 scalar

  char* ws = (char*)d_ws;
  unsigned short* K        = (unsigned short*)ws;                   // 32 MiB
  unsigned long long* u_ep = (unsigned long long*)(ws + 33554432);  // 320 KiB
  unsigned long long* v_ep = (unsigned long long*)(ws + 33554432 + 327680);
  unsigned int* flags      = (unsigned int*)(ws + 33554432 + 655360); // 16 KiB
  float* out = (float*)d_out;

  zero_flags<<<1, 256, 0, stream>>>(flags);
  sinkhorn_all<<<NBLK, 256, 0, stream>>>(alpha, beta, C, epsp, K, u_ep, v_ep,
                                         flags, out);
}